// Round 20
// baseline (99.733 us; speedup 1.0000x reference)
//
#include <hip/hip_runtime.h>
#include <stdint.h>

typedef unsigned short u16;
typedef short s16x8 __attribute__((ext_vector_type(8)));
typedef __bf16 bf16x8 __attribute__((ext_vector_type(8)));
typedef _Float16 f16x8 __attribute__((ext_vector_type(8)));
typedef float f32x4 __attribute__((ext_vector_type(4)));

#define SEQ    1024
#define DMODEL 1024
#define NB     4
#define NH     16
#define DH     64
#define QBLK   128
#define KVB    64
#define LOG2E  1.4426950408889634f
#define ROPE_C (-13.287712379549449f / 32.0f)   // log2(10000)/(-32)

// ---------- scalar conversion helpers ----------
__device__ __forceinline__ u16 f2bf(float f) {
  uint32_t u = __builtin_bit_cast(uint32_t, f);
  u += 0x7fffu + ((u >> 16) & 1u);   // round-to-nearest-even
  return (u16)(u >> 16);
}
__device__ __forceinline__ u16 f2bf_rz(float f) {   // truncate (p>=0; bias cancels in P/l)
  return (u16)(__builtin_bit_cast(uint32_t, f) >> 16);
}
__device__ __forceinline__ float bf2f(u16 h) {
  uint32_t u = ((uint32_t)h) << 16;
  return __builtin_bit_cast(float, u);
}
__device__ __forceinline__ u16 f2h(float f) {       // f32 -> fp16 RNE
  return __builtin_bit_cast(u16, (_Float16)f);
}
__device__ __forceinline__ float h2f(u16 u) {
  return (float)__builtin_bit_cast(_Float16, u);
}

#define MFMA16(a, b, c)  __builtin_amdgcn_mfma_f32_16x16x32_bf16((a), (b), (c), 0, 0, 0)
#define MFMA16H(a, b, c) __builtin_amdgcn_mfma_f32_16x16x32_f16((a), (b), (c), 0, 0, 0)

template<bool F16>
__device__ __forceinline__ f32x4 MF(s16x8 a, s16x8 b, f32x4 c) {
  if constexpr (F16)
    return MFMA16H(__builtin_bit_cast(f16x8, a), __builtin_bit_cast(f16x8, b), c);
  else
    return MFMA16(__builtin_bit_cast(bf16x8, a), __builtin_bit_cast(bf16x8, b), c);
}

// ---------- async global->LDS (16B) ----------
__device__ __forceinline__ void gload_lds16(const u16* g, uintptr_t lds_addr) {
  __builtin_amdgcn_global_load_lds(
      (__attribute__((address_space(1))) void*)(uintptr_t)g,
      (__attribute__((address_space(3))) void*)lds_addr,
      16, 0, 0);
}

// ---------------- fused cast: x,Wq,Wk,Wv -> fp16 ; Wo -> bf16 (one launch) ----------------
__global__ void cast_all_kernel(
    const float* __restrict__ x, const float* __restrict__ wq,
    const float* __restrict__ wk, const float* __restrict__ wv,
    const float* __restrict__ wo,
    u16* __restrict__ xd, u16* __restrict__ wqd, u16* __restrict__ wkd,
    u16* __restrict__ wvd, u16* __restrict__ wod)
{
  const int NX = (NB * SEQ * DMODEL) / 8;   // 524288 chunks
  const int NW = (DMODEL * DMODEL) / 8;     // 131072 chunks
  int c = blockIdx.x * blockDim.x + threadIdx.x;
  const float* src; u16* dst; bool tobf = false;
  if (c < NX)                { src = x;  dst = xd; }
  else if ((c -= NX) < NW)   { src = wq; dst = wqd; }
  else if ((c -= NW) < NW)   { src = wk; dst = wkd; }
  else if ((c -= NW) < NW)   { src = wv; dst = wvd; }
  else if ((c -= NW) < NW)   { src = wo; dst = wod; tobf = true; }
  else return;
  float f[8];
  float4 v0 = *(const float4*)(src + (size_t)c * 8);
  float4 v1 = *(const float4*)(src + (size_t)c * 8 + 4);
  f[0] = v0.x; f[1] = v0.y; f[2] = v0.z; f[3] = v0.w;
  f[4] = v1.x; f[5] = v1.y; f[6] = v1.z; f[7] = v1.w;
  union { u16 u[8]; uint4 v; } H;
#pragma unroll
  for (int e = 0; e < 8; ++e) H.u[e] = tobf ? f2bf(f[e]) : f2h(f[e]);
  *(uint4*)(dst + (size_t)c * 8) = H.v;
}

// ---------------- RoPE on fp16 K only (Q is rotated in-register in attn) ----------------
__global__ void rope_k_kernel(u16* __restrict__ K) {
  int p = blockIdx.x * blockDim.x + threadIdx.x;   // M * D/2 pairs
  int row = p >> 9;           // 512 pairs per row
  int pi  = p & 511;
  int t   = row & (SEQ - 1);
  int fi  = pi & 31;
  float inv = exp2f((float)fi * ROPE_C);   // 10000^(-fi/32)
  float ang = (float)t * inv;
  float sn, cs;
  sincosf(ang, &sn, &cs);
  size_t off = (size_t)row * DMODEL + pi * 2;
  uint32_t v = *(uint32_t*)(K + off);
  float e = h2f((u16)(v & 0xffffu));
  float o = h2f((u16)(v >> 16));
  float re = e * cs - o * sn;
  float ro = e * sn + o * cs;
  *(uint32_t*)(K + off) = (uint32_t)f2h(re) | ((uint32_t)f2h(ro) << 16);
}

// ---------------- QKV projection, shared-A pair blocks (R18-validated) ----------------
// z=0 (pair): stage A + Bq + Bk per K-step (48 KB), 64 MFMA/wave, two acc banks.
// z=1 (V): stage A + Bv (32 KB), Vt epilogue. Serial-drain loop.
__global__ __launch_bounds__(256, 2) void qkv_kernel(
    const u16* __restrict__ A, const u16* __restrict__ Bq,
    const u16* __restrict__ Bk, const u16* __restrict__ Bv,
    u16* __restrict__ Cq, u16* __restrict__ Ck, u16* __restrict__ VT,
    int M, int N, int K)
{
  __shared__ __align__(16) u16 sA [128 * 64];   // 16 KB
  __shared__ __align__(16) u16 sB0[128 * 64];   // 16 KB
  __shared__ __align__(16) u16 sB1[128 * 64];   // 16 KB (pair blocks only)
  const int t = threadIdx.x, lane = t & 63;
  const int wave = t >> 6;
  const int g = lane >> 4, cl = lane & 15;
  const bool pair = (blockIdx.z == 0);
  const int n0 = blockIdx.x * 128, m0 = blockIdx.y * 128;
  const int wr = wave >> 1, wc = wave & 1;

  int srow[4], scol[4], soff[4];
#pragma unroll
  for (int j = 0; j < 4; ++j) {
    int c = j * 256 + t;
    srow[j] = c >> 3;
    scol[j] = ((c & 7) ^ (srow[j] & 7)) * 8;
    soff[j] = c * 16;
  }

  f32x4 acc0[4][4] = {};
  f32x4 acc1[4][4] = {};

  for (int k0 = 0; k0 < K; k0 += 64) {
#pragma unroll
    for (int j = 0; j < 4; ++j)
      gload_lds16(A + (size_t)(m0 + srow[j]) * K + k0 + scol[j], (uintptr_t)sA + soff[j]);
    if (pair) {
#pragma unroll
      for (int j = 0; j < 4; ++j) {
        gload_lds16(Bq + (size_t)(n0 + srow[j]) * K + k0 + scol[j], (uintptr_t)sB0 + soff[j]);
        gload_lds16(Bk + (size_t)(n0 + srow[j]) * K + k0 + scol[j], (uintptr_t)sB1 + soff[j]);
      }
    } else {
#pragma unroll
      for (int j = 0; j < 4; ++j)
        gload_lds16(Bv + (size_t)(n0 + srow[j]) * K + k0 + scol[j], (uintptr_t)sB0 + soff[j]);
    }
    __syncthreads();   // drains vmcnt(0): staging landed

    s16x8 af[4][2];
#pragma unroll
    for (int m = 0; m < 4; ++m) {
      int row = wr * 64 + m * 16 + cl;
#pragma unroll
      for (int kk = 0; kk < 2; ++kk)
        af[m][kk] = *(const s16x8*)&sA[row * 64 + (((kk * 4 + g) ^ (row & 7)) * 8)];
    }
#pragma unroll
    for (int n = 0; n < 4; ++n) {
      int row = wc * 64 + n * 16 + cl;
      int o0 = row * 64 + ((g ^ (row & 7)) * 8);
      int o1 = row * 64 + (((4 + g) ^ (row & 7)) * 8);
      s16x8 b0 = *(const s16x8*)&sB0[o0];
      s16x8 b1 = *(const s16x8*)&sB0[o1];
#pragma unroll
      for (int m = 0; m < 4; ++m) {
        acc0[m][n] = MF<true>(af[m][0], b0, acc0[m][n]);
        acc0[m][n] = MF<true>(af[m][1], b1, acc0[m][n]);
      }
      if (pair) {
        s16x8 c0 = *(const s16x8*)&sB1[o0];
        s16x8 c1 = *(const s16x8*)&sB1[o1];
#pragma unroll
        for (int m = 0; m < 4; ++m) {
          acc1[m][n] = MF<true>(af[m][0], c0, acc1[m][n]);
          acc1[m][n] = MF<true>(af[m][1], c1, acc1[m][n]);
        }
      }
    }
    __syncthreads();
  }

  // epilogue: C/D layout col=lane&15, row=(lane>>4)*4+reg  [m89]
  if (pair) {
#pragma unroll
    for (int m = 0; m < 4; ++m)
#pragma unroll
      for (int n = 0; n < 4; ++n)
#pragma unroll
        for (int r = 0; r < 4; ++r) {
          int row = m0 + wr * 64 + m * 16 + g * 4 + r;
          int col = n0 + wc * 64 + n * 16 + cl;
          Cq[(size_t)row * N + col] = f2h(acc0[m][n][r]);
          Ck[(size_t)row * N + col] = f2h(acc1[m][n][r]);
        }
  } else {
#pragma unroll
    for (int m = 0; m < 4; ++m)
#pragma unroll
      for (int n = 0; n < 4; ++n) {
        int row0 = m0 + wr * 64 + m * 16 + g * 4;
        int col = n0 + wc * 64 + n * 16 + cl;
        union { u16 u[4]; uint2 v; } pk;
#pragma unroll
        for (int r = 0; r < 4; ++r) pk.u[r] = f2bf(acc0[m][n][r]);
        *(uint2*)&VT[(size_t)col * M + row0] = pk.v;
      }
  }
}

// ---------------- Wo GEMM: 128x64 tile, counted-vmcnt dbuf (R17-validated) ----------------
__global__ __launch_bounds__(256) void gemm_wo_kernel(
    const u16* __restrict__ A, const u16* __restrict__ B,
    float* __restrict__ CF, int M, int N, int K)
{
  constexpr int BN = 64;
  __shared__ __align__(16) u16 sA[2][128 * 64];  // 2 x 16 KB
  __shared__ __align__(16) u16 sB[2][BN * 64];   // 2 x 8 KB
  const int t = threadIdx.x, lane = t & 63;
  const int wave = t >> 6;
  const int g = lane >> 4, cl = lane & 15;
  const int n0 = blockIdx.x * BN, m0 = blockIdx.y * 128;
  const int wr = wave >> 1, wc = wave & 1;

  int srow[4], scol[4], soff[4];
#pragma unroll
  for (int j = 0; j < 4; ++j) {
    int c = j * 256 + t;
    srow[j] = c >> 3;
    scol[j] = ((c & 7) ^ (srow[j] & 7)) * 8;
    soff[j] = c * 16;
  }

  f32x4 acc[4][2] = {};

  // prologue: stage k0=0 into buffer 0 (6 loads/thread)
#pragma unroll
  for (int j = 0; j < 4; ++j)
    gload_lds16(A + (size_t)(m0 + srow[j]) * K + scol[j], (uintptr_t)&sA[0][0] + soff[j]);
#pragma unroll
  for (int j = 0; j < 2; ++j)
    gload_lds16(B + (size_t)(n0 + srow[j]) * K + scol[j], (uintptr_t)&sB[0][0] + soff[j]);

  int cur = 0;
  for (int k0 = 0; k0 < K; k0 += 64) {
    const bool hasnext = (k0 + 64 < K);   // block-uniform
    if (hasnext) {
      const int nk = k0 + 64;
#pragma unroll
      for (int j = 0; j < 4; ++j)
        gload_lds16(A + (size_t)(m0 + srow[j]) * K + nk + scol[j],
                    (uintptr_t)&sA[cur ^ 1][0] + soff[j]);
#pragma unroll
      for (int j = 0; j < 2; ++j)
        gload_lds16(B + (size_t)(n0 + srow[j]) * K + nk + scol[j],
                    (uintptr_t)&sB[cur ^ 1][0] + soff[j]);
      asm volatile("s_waitcnt vmcnt(6)" ::: "memory");  // prev tile only
    } else {
      asm volatile("s_waitcnt vmcnt(0)" ::: "memory");
    }
    __builtin_amdgcn_s_barrier();

    s16x8 af[4][2];
#pragma unroll
    for (int m = 0; m < 4; ++m) {
      int row = wr * 64 + m * 16 + cl;
#pragma unroll
      for (int kk = 0; kk < 2; ++kk)
        af[m][kk] = *(const s16x8*)&sA[cur][row * 64 + (((kk * 4 + g) ^ (row & 7)) * 8)];
    }
#pragma unroll
    for (int n = 0; n < 2; ++n) {
      int row = wc * 32 + n * 16 + cl;
      s16x8 b0 = *(const s16x8*)&sB[cur][row * 64 + ((g ^ (row & 7)) * 8)];
      s16x8 b1 = *(const s16x8*)&sB[cur][row * 64 + (((4 + g) ^ (row & 7)) * 8)];
#pragma unroll
      for (int m = 0; m < 4; ++m) {
        acc[m][n] = MF<false>(af[m][0], b0, acc[m][n]);
        acc[m][n] = MF<false>(af[m][1], b1, acc[m][n]);
      }
    }
    __builtin_amdgcn_s_barrier();
    cur ^= 1;
  }

#pragma unroll
  for (int m = 0; m < 4; ++m)
#pragma unroll
    for (int n = 0; n < 2; ++n)
#pragma unroll
      for (int r = 0; r < 4; ++r) {
        int row = m0 + wr * 64 + m * 16 + g * 4 + r;
        int col = n0 + wc * 32 + n * 16 + cl;
        CF[(size_t)row * N + col] = acc[m][n][r];
      }
}

// ---------------- flash attention: fp16 QK^T (Q RoPE'd in-register), bf16 PV ----------------
// R18-validated 4-wave version (99.6us, absmax 0.0173). The 8-wave restructure
// (R19) failed correctness for undetermined reasons — reverted; do not re-attempt
// without a standalone refcheck harness.
__global__ __launch_bounds__(256, 2) void attn_kernel(
    const u16* __restrict__ Q, const u16* __restrict__ K,
    const u16* __restrict__ Vt,
    u16* __restrict__ Oh)
{
  __shared__ __align__(16) u16 sK [2][KVB * 64];   // fp16 [buf][key][d]  16KB
  __shared__ __align__(16) u16 sVt[2][DH * KVB];   // bf16 [buf][d][key]  16KB
  __shared__ __align__(16) u16 sP[128 * 72];       // bf16, 18KB, wave-private rows

  const int t = threadIdx.x, lane = t & 63, wave = t >> 6;
  const int g = lane >> 4, cl = lane & 15;
  const int h = blockIdx.x & (NH - 1), b = blockIdx.x >> 4;
  const int y = blockIdx.y;
  const int qi = (y < 4) ? (7 - y) : (y - 4);  // paired work balance + heavy-first
  const int q0 = qi * QBLK;
  const size_t rowbase = (size_t)b * SEQ;
  const int colbase = h * DH;
  const int MT = NB * SEQ;

  const u16* Kb  = K + rowbase * DMODEL + colbase;
  const u16* Vtb = Vt + (size_t)(h * DH) * MT + b * SEQ;

  int srow[2], scol[2], soff[2];
#pragma unroll
  for (int j = 0; j < 2; ++j) {
    int c = j * 256 + t;
    srow[j] = c >> 3;
    scol[j] = ((c & 7) ^ (srow[j] & 7)) * 8;
    soff[j] = c * 16;
  }

  // loop-invariant LDS read offsets
  int koff0[4], koff1[4];
#pragma unroll
  for (int n = 0; n < 4; ++n) {
    int row = n * 16 + cl;
    koff0[n] = row * 64 + ((g ^ (row & 7)) * 8);
    koff1[n] = row * 64 + (((4 + g) ^ (row & 7)) * 8);
  }
  int paoff[2][2];
#pragma unroll
  for (int kk = 0; kk < 2; ++kk) {
    paoff[kk][0] = (wave * 32 + cl) * 72 + kk * 32 + g * 8;
    paoff[kk][1] = (wave * 32 + 16 + cl) * 72 + kk * 32 + g * 8;
  }

  // Q fragments fp16 with in-register RoPE (pairs are adjacent elems 2j,2j+1)
  f16x8 qf[2][2];
#pragma unroll
  for (int mf = 0; mf < 2; ++mf) {
    int qrow = q0 + wave * 32 + mf * 16 + cl;
    const u16* pq = Q + (rowbase + qrow) * DMODEL + colbase + g * 8;
    s16x8 raw0 = *(const s16x8*)pq;
    s16x8 raw1 = *(const s16x8*)(pq + 32);
    f16x8 r0, r1;
#pragma unroll
    for (int j = 0; j < 4; ++j) {
      float sn, cs;
      // frag0: head-local d = g*8 + 2j -> fi = 4g + j
      sincosf((float)qrow * exp2f((float)(4 * g + j) * ROPE_C), &sn, &cs);
      float e = h2f((u16)raw0[2 * j]), o = h2f((u16)raw0[2 * j + 1]);
      r0[2 * j]     = (_Float16)(e * cs - o * sn);
      r0[2 * j + 1] = (_Float16)(e * sn + o * cs);
      // frag1: d = 32 + g*8 + 2j -> fi = 16 + 4g + j
      sincosf((float)qrow * exp2f((float)(16 + 4 * g + j) * ROPE_C), &sn, &cs);
      e = h2f((u16)raw1[2 * j]); o = h2f((u16)raw1[2 * j + 1]);
      r1[2 * j]     = (_Float16)(e * cs - o * sn);
      r1[2 * j + 1] = (_Float16)(e * sn + o * cs);
    }
    qf[mf][0] = r0; qf[mf][1] = r1;
  }

  bf16x8 ones;
#pragma unroll
  for (int e = 0; e < 8; ++e) ones[e] = (__bf16)1.0f;

  f32x4 o_acc[2][4] = {};
  f32x4 o_l[2] = {};

  const int last = 2 * qi + 1;
  const int wrow0 = q0 + wave * 32;
  const int prow0 = wave * 32;

  // prologue: stage tile 0 into buffer 0
#pragma unroll
  for (int j = 0; j < 2; ++j) {
    gload_lds16(Kb + (size_t)srow[j] * DMODEL + scol[j],  (uintptr_t)&sK[0][0] + soff[j]);
    gload_lds16(Vtb + (size_t)srow[j] * MT + scol[j],     (uintptr_t)&sVt[0][0] + soff[j]);
  }
  __syncthreads();

  int cur = 0;
  for (int kt = 0; kt <= last; ++kt) {
    const int kv0 = kt * KVB;
    // issue next tile's staging FIRST (hidden under this tile's compute)
    if (kt < last) {
      const int nk = kv0 + KVB;
#pragma unroll
      for (int j = 0; j < 2; ++j) {
        gload_lds16(Kb + (size_t)(nk + srow[j]) * DMODEL + scol[j],
                    (uintptr_t)&sK[cur ^ 1][0] + soff[j]);
        gload_lds16(Vtb + (size_t)srow[j] * MT + nk + scol[j],
                    (uintptr_t)&sVt[cur ^ 1][0] + soff[j]);
      }
    }

    const bool skip = (wrow0 + 31) < kv0;   // wave fully masked (diag tiles)
    if (!skip) {
      const bool needmask = (kv0 + 63) > wrow0;

      // QK^T: fp16 single-term
      f32x4 s[2][4];
      __builtin_amdgcn_s_setprio(1);
#pragma unroll
      for (int n = 0; n < 4; ++n) {
        f16x8 k0 = __builtin_bit_cast(f16x8, *(const s16x8*)&sK[cur][koff0[n]]);
        f16x8 k1 = __builtin_bit_cast(f16x8, *(const s16x8*)&sK[cur][koff1[n]]);
#pragma unroll
        for (int mf = 0; mf < 2; ++mf) {
          f32x4 zz = {};
          zz = MFMA16H(qf[mf][0], k0, zz);
          zz = MFMA16H(qf[mf][1], k1, zz);
          s[mf][n] = zz;
        }
      }
      __builtin_amdgcn_s_setprio(0);

      // no-max softmax: p = exp2(s*log2e), zeroed past the diagonal
#pragma unroll
      for (int mf = 0; mf < 2; ++mf) {
#pragma unroll
        for (int r = 0; r < 4; ++r) {
          int qg = wrow0 + mf * 16 + g * 4 + r;
          int prow = prow0 + mf * 16 + g * 4 + r;
#pragma unroll
          for (int n = 0; n < 4; ++n) {
            float p = exp2f(s[mf][n][r] * LOG2E);
            if (needmask && (kv0 + n * 16 + cl > qg)) p = 0.0f;
            sP[prow * 72 + n * 16 + cl] = f2bf_rz(p);
          }
        }
      }

      // PV: O += P(32x64)*Vt ; l += P*1 (bf16 MFMA)
      __builtin_amdgcn_s_setprio(1);
#pragma unroll
      for (int kk = 0; kk < 2; ++kk) {
        bf16x8 pa0 = *(const bf16x8*)&sP[paoff[kk][0]];
        bf16x8 pa1 = *(const bf16x8*)&sP[paoff[kk][1]];
#pragma unroll
        for (int n = 0; n < 4; ++n) {
          bf16x8 vf = *(const bf16x8*)&sVt[cur][(kk == 0) ? koff0[n] : koff1[n]];
          o_acc[0][n] = MFMA16(pa0, vf, o_acc[0][n]);
          o_acc[1][n] = MFMA16(pa1, vf, o_acc[1][n]);
        }
        o_l[0] = MFMA16(pa0, ones, o_l[0]);
        o_l[1] = MFMA16(pa1, ones, o_l[1]);
      }
      __builtin_amdgcn_s_setprio(0);
    }

    __syncthreads();   // drains vmcnt(0): prefetch landed; frees buf cur
    cur ^= 1;
  }

  // epilogue: normalize by l, store bf16 (feeds bf16 Wo GEMM)
#pragma unroll
  for (int mf = 0; mf < 2; ++mf)
#pragma unroll
    for (int n = 0; n < 4; ++n)
#pragma unroll
      for (int r = 0; r < 4; ++r) {
        float ov = o_acc[mf][n][r] / o_l[mf][r];
        int qrow = q0 + wave * 32 + mf * 16 + g * 4 + r;
        size_t idx = (rowbase + qrow) * DMODEL + colbase + n * 16 + cl;
        Oh[idx] = f2bf(ov);
      }
}

extern "C" void kernel_launch(void* const* d_in, const int* in_sizes, int n_in,
                              void* d_out, int out_size, void* d_ws, size_t ws_size,
                              hipStream_t stream) {
  const float* x  = (const float*)d_in[0];
  const float* Wq = (const float*)d_in[1];
  const float* Wk = (const float*)d_in[2];
  const float* Wv = (const float*)d_in[3];
  const float* Wo = (const float*)d_in[4];
  float* out = (float*)d_out;

  const int M = NB * SEQ;      // 4096
  const int D = DMODEL;        // 1024
  char* ws = (char*)d_ws;
  const size_t MB = 1u << 20;
  u16* xh16 = (u16*)(ws + 0 * MB);    // 8 MB fp16
  u16* qh16 = (u16*)(ws + 8 * MB);    // 8 MB fp16 (unrotated; attn rotates Q)
  u16* kh16 = (u16*)(ws + 16 * MB);   // 8 MB fp16 (rotated in place)
  u16* vt   = (u16*)(ws + 24 * MB);   // 8 MB bf16, transposed [1024][4096]
  u16* oh   = (u16*)(ws + 40 * MB);   // 8 MB bf16
  u16* wq16 = (u16*)(ws + 48 * MB);   // 2 MB each
  u16* wk16 = (u16*)(ws + 50 * MB);
  u16* wv16 = (u16*)(ws + 52 * MB);
  u16* wob  = (u16*)(ws + 54 * MB);

  // one fused cast launch: x,Wq,Wk,Wv -> fp16 ; Wo -> bf16
  {
    int total = M * D / 8 + 4 * (D * D / 8);
    cast_all_kernel<<<(total + 255) / 256, 256, 0, stream>>>(
        x, Wq, Wk, Wv, Wo, xh16, wq16, wk16, wv16, wob);
  }

  // QKV: z=0 fused Q+K shared-A pair blocks; z=1 V (Vt out). 512 blocks.
  qkv_kernel<<<dim3(D / 128, M / 128, 2), 256, 0, stream>>>(
      xh16, wq16, wk16, wv16, qh16, kh16, vt, M, D, D);

  // RoPE on K only (Q rotated in attn)
  rope_k_kernel<<<(M * (D / 2)) / 256, 256, 0, stream>>>(kh16);

  // causal flash attention: 512 blocks of 4 waves, pair-balanced heavy-first
  attn_kernel<<<dim3(NH * NB, 8), 256, 0, stream>>>(qh16, kh16, vt, oh);

  // output projection: bf16, 128x64 tile, counted-vmcnt dbuf, direct f32 out
  gemm_wo_kernel<<<dim3(D / 64, M / 128, 1), 256, 0, stream>>>(
      oh, wob, out, M, D, D);
}

// Round 21
// 98.199 us; speedup vs baseline: 1.0156x; 1.0156x over previous
//
#include <hip/hip_runtime.h>
#include <stdint.h>

typedef unsigned short u16;
typedef short s16x8 __attribute__((ext_vector_type(8)));
typedef __bf16 bf16x8 __attribute__((ext_vector_type(8)));
typedef _Float16 f16x8 __attribute__((ext_vector_type(8)));
typedef float f32x4 __attribute__((ext_vector_type(4)));

#define SEQ    1024
#define DMODEL 1024
#define NB     4
#define NH     16
#define DH     64
#define QBLK   128
#define KVB    64
#define LOG2E  1.4426950408889634f
#define ROPE_C (-13.287712379549449f / 32.0f)   // log2(10000)/(-32)

// ---------- scalar conversion helpers ----------
__device__ __forceinline__ u16 f2bf(float f) {
  uint32_t u = __builtin_bit_cast(uint32_t, f);
  u += 0x7fffu + ((u >> 16) & 1u);   // round-to-nearest-even
  return (u16)(u >> 16);
}
__device__ __forceinline__ u16 f2bf_rz(float f) {   // truncate (p>=0; bias cancels in P/l)
  return (u16)(__builtin_bit_cast(uint32_t, f) >> 16);
}
__device__ __forceinline__ float bf2f(u16 h) {
  uint32_t u = ((uint32_t)h) << 16;
  return __builtin_bit_cast(float, u);
}
__device__ __forceinline__ u16 f2h(float f) {       // f32 -> fp16 RNE
  return __builtin_bit_cast(u16, (_Float16)f);
}
__device__ __forceinline__ float h2f(u16 u) {
  return (float)__builtin_bit_cast(_Float16, u);
}

#define MFMA16(a, b, c)  __builtin_amdgcn_mfma_f32_16x16x32_bf16((a), (b), (c), 0, 0, 0)
#define MFMA16H(a, b, c) __builtin_amdgcn_mfma_f32_16x16x32_f16((a), (b), (c), 0, 0, 0)

template<bool F16>
__device__ __forceinline__ f32x4 MF(s16x8 a, s16x8 b, f32x4 c) {
  if constexpr (F16)
    return MFMA16H(__builtin_bit_cast(f16x8, a), __builtin_bit_cast(f16x8, b), c);
  else
    return MFMA16(__builtin_bit_cast(bf16x8, a), __builtin_bit_cast(bf16x8, b), c);
}

// ---------- async global->LDS (16B) ----------
__device__ __forceinline__ void gload_lds16(const u16* g, uintptr_t lds_addr) {
  __builtin_amdgcn_global_load_lds(
      (__attribute__((address_space(1))) void*)(uintptr_t)g,
      (__attribute__((address_space(3))) void*)lds_addr,
      16, 0, 0);
}

// ---------------- fused cast: x,Wq,Wk,Wv -> fp16 ; Wo -> bf16 (one launch) ----------------
__global__ void cast_all_kernel(
    const float* __restrict__ x, const float* __restrict__ wq,
    const float* __restrict__ wk, const float* __restrict__ wv,
    const float* __restrict__ wo,
    u16* __restrict__ xd, u16* __restrict__ wqd, u16* __restrict__ wkd,
    u16* __restrict__ wvd, u16* __restrict__ wod)
{
  const int NX = (NB * SEQ * DMODEL) / 8;   // 524288 chunks
  const int NW = (DMODEL * DMODEL) / 8;     // 131072 chunks
  int c = blockIdx.x * blockDim.x + threadIdx.x;
  const float* src; u16* dst; bool tobf = false;
  if (c < NX)                { src = x;  dst = xd; }
  else if ((c -= NX) < NW)   { src = wq; dst = wqd; }
  else if ((c -= NW) < NW)   { src = wk; dst = wkd; }
  else if ((c -= NW) < NW)   { src = wv; dst = wvd; }
  else if ((c -= NW) < NW)   { src = wo; dst = wod; tobf = true; }
  else return;
  float f[8];
  float4 v0 = *(const float4*)(src + (size_t)c * 8);
  float4 v1 = *(const float4*)(src + (size_t)c * 8 + 4);
  f[0] = v0.x; f[1] = v0.y; f[2] = v0.z; f[3] = v0.w;
  f[4] = v1.x; f[5] = v1.y; f[6] = v1.z; f[7] = v1.w;
  union { u16 u[8]; uint4 v; } H;
#pragma unroll
  for (int e = 0; e < 8; ++e) H.u[e] = tobf ? f2bf(f[e]) : f2h(f[e]);
  *(uint4*)(dst + (size_t)c * 8) = H.v;
}

// ---------------- RoPE on fp16 K (one sincosf per 16 pairs) ----------------
// Angle depends only on (t = row mod SEQ, fi = pi & 31): the 16 pairs
// pi = fi + 32j of a row share one angle. One thread per (row, fi):
// 1 sincosf + 16 stride-64B rotations (lanes 0-31 = fi 0-31 of one row ->
// 128B coalesced segments). 16x less VALU than the per-pair version;
// bitwise-identical per-element math.
__global__ void rope_k_kernel(u16* __restrict__ K) {
  int idx = blockIdx.x * blockDim.x + threadIdx.x;   // M * 32
  int row = idx >> 5;
  int fi  = idx & 31;
  int t   = row & (SEQ - 1);
  float inv = exp2f((float)fi * ROPE_C);   // 10000^(-fi/32)
  float sn, cs;
  sincosf((float)t * inv, &sn, &cs);
  u16* base = K + (size_t)row * DMODEL;
#pragma unroll
  for (int j = 0; j < 16; ++j) {
    int pi = fi + 32 * j;
    uint32_t v = *(uint32_t*)(base + pi * 2);
    float e = h2f((u16)(v & 0xffffu));
    float o = h2f((u16)(v >> 16));
    *(uint32_t*)(base + pi * 2) =
        (uint32_t)f2h(e * cs - o * sn) | ((uint32_t)f2h(e * sn + o * cs) << 16);
  }
}

// ---------------- QKV projection, shared-A pair blocks (R18-validated) ----------------
// z=0 (pair): stage A + Bq + Bk per K-step (48 KB), 64 MFMA/wave, two acc banks.
// z=1 (V): stage A + Bv (32 KB), Vt epilogue. Serial-drain loop.
__global__ __launch_bounds__(256, 2) void qkv_kernel(
    const u16* __restrict__ A, const u16* __restrict__ Bq,
    const u16* __restrict__ Bk, const u16* __restrict__ Bv,
    u16* __restrict__ Cq, u16* __restrict__ Ck, u16* __restrict__ VT,
    int M, int N, int K)
{
  __shared__ __align__(16) u16 sA [128 * 64];   // 16 KB
  __shared__ __align__(16) u16 sB0[128 * 64];   // 16 KB
  __shared__ __align__(16) u16 sB1[128 * 64];   // 16 KB (pair blocks only)
  const int t = threadIdx.x, lane = t & 63;
  const int wave = t >> 6;
  const int g = lane >> 4, cl = lane & 15;
  const bool pair = (blockIdx.z == 0);
  const int n0 = blockIdx.x * 128, m0 = blockIdx.y * 128;
  const int wr = wave >> 1, wc = wave & 1;

  int srow[4], scol[4], soff[4];
#pragma unroll
  for (int j = 0; j < 4; ++j) {
    int c = j * 256 + t;
    srow[j] = c >> 3;
    scol[j] = ((c & 7) ^ (srow[j] & 7)) * 8;
    soff[j] = c * 16;
  }

  f32x4 acc0[4][4] = {};
  f32x4 acc1[4][4] = {};

  for (int k0 = 0; k0 < K; k0 += 64) {
#pragma unroll
    for (int j = 0; j < 4; ++j)
      gload_lds16(A + (size_t)(m0 + srow[j]) * K + k0 + scol[j], (uintptr_t)sA + soff[j]);
    if (pair) {
#pragma unroll
      for (int j = 0; j < 4; ++j) {
        gload_lds16(Bq + (size_t)(n0 + srow[j]) * K + k0 + scol[j], (uintptr_t)sB0 + soff[j]);
        gload_lds16(Bk + (size_t)(n0 + srow[j]) * K + k0 + scol[j], (uintptr_t)sB1 + soff[j]);
      }
    } else {
#pragma unroll
      for (int j = 0; j < 4; ++j)
        gload_lds16(Bv + (size_t)(n0 + srow[j]) * K + k0 + scol[j], (uintptr_t)sB0 + soff[j]);
    }
    __syncthreads();   // drains vmcnt(0): staging landed

    s16x8 af[4][2];
#pragma unroll
    for (int m = 0; m < 4; ++m) {
      int row = wr * 64 + m * 16 + cl;
#pragma unroll
      for (int kk = 0; kk < 2; ++kk)
        af[m][kk] = *(const s16x8*)&sA[row * 64 + (((kk * 4 + g) ^ (row & 7)) * 8)];
    }
#pragma unroll
    for (int n = 0; n < 4; ++n) {
      int row = wc * 64 + n * 16 + cl;
      int o0 = row * 64 + ((g ^ (row & 7)) * 8);
      int o1 = row * 64 + (((4 + g) ^ (row & 7)) * 8);
      s16x8 b0 = *(const s16x8*)&sB0[o0];
      s16x8 b1 = *(const s16x8*)&sB0[o1];
#pragma unroll
      for (int m = 0; m < 4; ++m) {
        acc0[m][n] = MF<true>(af[m][0], b0, acc0[m][n]);
        acc0[m][n] = MF<true>(af[m][1], b1, acc0[m][n]);
      }
      if (pair) {
        s16x8 c0 = *(const s16x8*)&sB1[o0];
        s16x8 c1 = *(const s16x8*)&sB1[o1];
#pragma unroll
        for (int m = 0; m < 4; ++m) {
          acc1[m][n] = MF<true>(af[m][0], c0, acc1[m][n]);
          acc1[m][n] = MF<true>(af[m][1], c1, acc1[m][n]);
        }
      }
    }
    __syncthreads();
  }

  // epilogue: C/D layout col=lane&15, row=(lane>>4)*4+reg  [m89]
  if (pair) {
#pragma unroll
    for (int m = 0; m < 4; ++m)
#pragma unroll
      for (int n = 0; n < 4; ++n)
#pragma unroll
        for (int r = 0; r < 4; ++r) {
          int row = m0 + wr * 64 + m * 16 + g * 4 + r;
          int col = n0 + wc * 64 + n * 16 + cl;
          Cq[(size_t)row * N + col] = f2h(acc0[m][n][r]);
          Ck[(size_t)row * N + col] = f2h(acc1[m][n][r]);
        }
  } else {
#pragma unroll
    for (int m = 0; m < 4; ++m)
#pragma unroll
      for (int n = 0; n < 4; ++n) {
        int row0 = m0 + wr * 64 + m * 16 + g * 4;
        int col = n0 + wc * 64 + n * 16 + cl;
        union { u16 u[4]; uint2 v; } pk;
#pragma unroll
        for (int r = 0; r < 4; ++r) pk.u[r] = f2bf(acc0[m][n][r]);
        *(uint2*)&VT[(size_t)col * M + row0] = pk.v;
      }
  }
}

// ---------------- Wo GEMM: 128x64 tile, counted-vmcnt dbuf (R17-validated) ----------------
__global__ __launch_bounds__(256) void gemm_wo_kernel(
    const u16* __restrict__ A, const u16* __restrict__ B,
    float* __restrict__ CF, int M, int N, int K)
{
  constexpr int BN = 64;
  __shared__ __align__(16) u16 sA[2][128 * 64];  // 2 x 16 KB
  __shared__ __align__(16) u16 sB[2][BN * 64];   // 2 x 8 KB
  const int t = threadIdx.x, lane = t & 63;
  const int wave = t >> 6;
  const int g = lane >> 4, cl = lane & 15;
  const int n0 = blockIdx.x * BN, m0 = blockIdx.y * 128;
  const int wr = wave >> 1, wc = wave & 1;

  int srow[4], scol[4], soff[4];
#pragma unroll
  for (int j = 0; j < 4; ++j) {
    int c = j * 256 + t;
    srow[j] = c >> 3;
    scol[j] = ((c & 7) ^ (srow[j] & 7)) * 8;
    soff[j] = c * 16;
  }

  f32x4 acc[4][2] = {};

  // prologue: stage k0=0 into buffer 0 (6 loads/thread)
#pragma unroll
  for (int j = 0; j < 4; ++j)
    gload_lds16(A + (size_t)(m0 + srow[j]) * K + scol[j], (uintptr_t)&sA[0][0] + soff[j]);
#pragma unroll
  for (int j = 0; j < 2; ++j)
    gload_lds16(B + (size_t)(n0 + srow[j]) * K + scol[j], (uintptr_t)&sB[0][0] + soff[j]);

  int cur = 0;
  for (int k0 = 0; k0 < K; k0 += 64) {
    const bool hasnext = (k0 + 64 < K);   // block-uniform
    if (hasnext) {
      const int nk = k0 + 64;
#pragma unroll
      for (int j = 0; j < 4; ++j)
        gload_lds16(A + (size_t)(m0 + srow[j]) * K + nk + scol[j],
                    (uintptr_t)&sA[cur ^ 1][0] + soff[j]);
#pragma unroll
      for (int j = 0; j < 2; ++j)
        gload_lds16(B + (size_t)(n0 + srow[j]) * K + nk + scol[j],
                    (uintptr_t)&sB[cur ^ 1][0] + soff[j]);
      asm volatile("s_waitcnt vmcnt(6)" ::: "memory");  // prev tile only
    } else {
      asm volatile("s_waitcnt vmcnt(0)" ::: "memory");
    }
    __builtin_amdgcn_s_barrier();

    s16x8 af[4][2];
#pragma unroll
    for (int m = 0; m < 4; ++m) {
      int row = wr * 64 + m * 16 + cl;
#pragma unroll
      for (int kk = 0; kk < 2; ++kk)
        af[m][kk] = *(const s16x8*)&sA[cur][row * 64 + (((kk * 4 + g) ^ (row & 7)) * 8)];
    }
#pragma unroll
    for (int n = 0; n < 2; ++n) {
      int row = wc * 32 + n * 16 + cl;
      s16x8 b0 = *(const s16x8*)&sB[cur][row * 64 + ((g ^ (row & 7)) * 8)];
      s16x8 b1 = *(const s16x8*)&sB[cur][row * 64 + (((4 + g) ^ (row & 7)) * 8)];
#pragma unroll
      for (int m = 0; m < 4; ++m) {
        acc[m][n] = MF<false>(af[m][0], b0, acc[m][n]);
        acc[m][n] = MF<false>(af[m][1], b1, acc[m][n]);
      }
    }
    __builtin_amdgcn_s_barrier();
    cur ^= 1;
  }

#pragma unroll
  for (int m = 0; m < 4; ++m)
#pragma unroll
    for (int n = 0; n < 2; ++n)
#pragma unroll
      for (int r = 0; r < 4; ++r) {
        int row = m0 + wr * 64 + m * 16 + g * 4 + r;
        int col = n0 + wc * 32 + n * 16 + cl;
        CF[(size_t)row * N + col] = acc[m][n][r];
      }
}

// ---------------- flash attention: fp16 QK^T (Q RoPE'd in-register), bf16 PV ----------------
// R18-validated 4-wave version (99.6us, absmax 0.0173). The 8-wave restructure
// (R19) failed correctness for undetermined reasons — reverted; do not re-attempt
// without a standalone refcheck harness.
__global__ __launch_bounds__(256, 2) void attn_kernel(
    const u16* __restrict__ Q, const u16* __restrict__ K,
    const u16* __restrict__ Vt,
    u16* __restrict__ Oh)
{
  __shared__ __align__(16) u16 sK [2][KVB * 64];   // fp16 [buf][key][d]  16KB
  __shared__ __align__(16) u16 sVt[2][DH * KVB];   // bf16 [buf][d][key]  16KB
  __shared__ __align__(16) u16 sP[128 * 72];       // bf16, 18KB, wave-private rows

  const int t = threadIdx.x, lane = t & 63, wave = t >> 6;
  const int g = lane >> 4, cl = lane & 15;
  const int h = blockIdx.x & (NH - 1), b = blockIdx.x >> 4;
  const int y = blockIdx.y;
  const int qi = (y < 4) ? (7 - y) : (y - 4);  // paired work balance + heavy-first
  const int q0 = qi * QBLK;
  const size_t rowbase = (size_t)b * SEQ;
  const int colbase = h * DH;
  const int MT = NB * SEQ;

  const u16* Kb  = K + rowbase * DMODEL + colbase;
  const u16* Vtb = Vt + (size_t)(h * DH) * MT + b * SEQ;

  int srow[2], scol[2], soff[2];
#pragma unroll
  for (int j = 0; j < 2; ++j) {
    int c = j * 256 + t;
    srow[j] = c >> 3;
    scol[j] = ((c & 7) ^ (srow[j] & 7)) * 8;
    soff[j] = c * 16;
  }

  // loop-invariant LDS read offsets
  int koff0[4], koff1[4];
#pragma unroll
  for (int n = 0; n < 4; ++n) {
    int row = n * 16 + cl;
    koff0[n] = row * 64 + ((g ^ (row & 7)) * 8);
    koff1[n] = row * 64 + (((4 + g) ^ (row & 7)) * 8);
  }
  int paoff[2][2];
#pragma unroll
  for (int kk = 0; kk < 2; ++kk) {
    paoff[kk][0] = (wave * 32 + cl) * 72 + kk * 32 + g * 8;
    paoff[kk][1] = (wave * 32 + 16 + cl) * 72 + kk * 32 + g * 8;
  }

  // Q fragments fp16 with in-register RoPE (pairs are adjacent elems 2j,2j+1)
  f16x8 qf[2][2];
#pragma unroll
  for (int mf = 0; mf < 2; ++mf) {
    int qrow = q0 + wave * 32 + mf * 16 + cl;
    const u16* pq = Q + (rowbase + qrow) * DMODEL + colbase + g * 8;
    s16x8 raw0 = *(const s16x8*)pq;
    s16x8 raw1 = *(const s16x8*)(pq + 32);
    f16x8 r0, r1;
#pragma unroll
    for (int j = 0; j < 4; ++j) {
      float sn, cs;
      // frag0: head-local d = g*8 + 2j -> fi = 4g + j
      sincosf((float)qrow * exp2f((float)(4 * g + j) * ROPE_C), &sn, &cs);
      float e = h2f((u16)raw0[2 * j]), o = h2f((u16)raw0[2 * j + 1]);
      r0[2 * j]     = (_Float16)(e * cs - o * sn);
      r0[2 * j + 1] = (_Float16)(e * sn + o * cs);
      // frag1: d = 32 + g*8 + 2j -> fi = 16 + 4g + j
      sincosf((float)qrow * exp2f((float)(16 + 4 * g + j) * ROPE_C), &sn, &cs);
      e = h2f((u16)raw1[2 * j]); o = h2f((u16)raw1[2 * j + 1]);
      r1[2 * j]     = (_Float16)(e * cs - o * sn);
      r1[2 * j + 1] = (_Float16)(e * sn + o * cs);
    }
    qf[mf][0] = r0; qf[mf][1] = r1;
  }

  bf16x8 ones;
#pragma unroll
  for (int e = 0; e < 8; ++e) ones[e] = (__bf16)1.0f;

  f32x4 o_acc[2][4] = {};
  f32x4 o_l[2] = {};

  const int last = 2 * qi + 1;
  const int wrow0 = q0 + wave * 32;
  const int prow0 = wave * 32;

  // prologue: stage tile 0 into buffer 0
#pragma unroll
  for (int j = 0; j < 2; ++j) {
    gload_lds16(Kb + (size_t)srow[j] * DMODEL + scol[j],  (uintptr_t)&sK[0][0] + soff[j]);
    gload_lds16(Vtb + (size_t)srow[j] * MT + scol[j],     (uintptr_t)&sVt[0][0] + soff[j]);
  }
  __syncthreads();

  int cur = 0;
  for (int kt = 0; kt <= last; ++kt) {
    const int kv0 = kt * KVB;
    // issue next tile's staging FIRST (hidden under this tile's compute)
    if (kt < last) {
      const int nk = kv0 + KVB;
#pragma unroll
      for (int j = 0; j < 2; ++j) {
        gload_lds16(Kb + (size_t)(nk + srow[j]) * DMODEL + scol[j],
                    (uintptr_t)&sK[cur ^ 1][0] + soff[j]);
        gload_lds16(Vtb + (size_t)srow[j] * MT + nk + scol[j],
                    (uintptr_t)&sVt[cur ^ 1][0] + soff[j]);
      }
    }

    const bool skip = (wrow0 + 31) < kv0;   // wave fully masked (diag tiles)
    if (!skip) {
      const bool needmask = (kv0 + 63) > wrow0;

      // QK^T: fp16 single-term
      f32x4 s[2][4];
      __builtin_amdgcn_s_setprio(1);
#pragma unroll
      for (int n = 0; n < 4; ++n) {
        f16x8 k0 = __builtin_bit_cast(f16x8, *(const s16x8*)&sK[cur][koff0[n]]);
        f16x8 k1 = __builtin_bit_cast(f16x8, *(const s16x8*)&sK[cur][koff1[n]]);
#pragma unroll
        for (int mf = 0; mf < 2; ++mf) {
          f32x4 zz = {};
          zz = MFMA16H(qf[mf][0], k0, zz);
          zz = MFMA16H(qf[mf][1], k1, zz);
          s[mf][n] = zz;
        }
      }
      __builtin_amdgcn_s_setprio(0);

      // no-max softmax: p = exp2(s*log2e), zeroed past the diagonal
#pragma unroll
      for (int mf = 0; mf < 2; ++mf) {
#pragma unroll
        for (int r = 0; r < 4; ++r) {
          int qg = wrow0 + mf * 16 + g * 4 + r;
          int prow = prow0 + mf * 16 + g * 4 + r;
#pragma unroll
          for (int n = 0; n < 4; ++n) {
            float p = exp2f(s[mf][n][r] * LOG2E);
            if (needmask && (kv0 + n * 16 + cl > qg)) p = 0.0f;
            sP[prow * 72 + n * 16 + cl] = f2bf_rz(p);
          }
        }
      }

      // PV: O += P(32x64)*Vt ; l += P*1 (bf16 MFMA)
      __builtin_amdgcn_s_setprio(1);
#pragma unroll
      for (int kk = 0; kk < 2; ++kk) {
        bf16x8 pa0 = *(const bf16x8*)&sP[paoff[kk][0]];
        bf16x8 pa1 = *(const bf16x8*)&sP[paoff[kk][1]];
#pragma unroll
        for (int n = 0; n < 4; ++n) {
          bf16x8 vf = *(const bf16x8*)&sVt[cur][(kk == 0) ? koff0[n] : koff1[n]];
          o_acc[0][n] = MFMA16(pa0, vf, o_acc[0][n]);
          o_acc[1][n] = MFMA16(pa1, vf, o_acc[1][n]);
        }
        o_l[0] = MFMA16(pa0, ones, o_l[0]);
        o_l[1] = MFMA16(pa1, ones, o_l[1]);
      }
      __builtin_amdgcn_s_setprio(0);
    }

    __syncthreads();   // drains vmcnt(0): prefetch landed; frees buf cur
    cur ^= 1;
  }

  // epilogue: normalize by l, store bf16 (feeds bf16 Wo GEMM)
#pragma unroll
  for (int mf = 0; mf < 2; ++mf)
#pragma unroll
    for (int n = 0; n < 4; ++n)
#pragma unroll
      for (int r = 0; r < 4; ++r) {
        float ov = o_acc[mf][n][r] / o_l[mf][r];
        int qrow = q0 + wave * 32 + mf * 16 + g * 4 + r;
        size_t idx = (rowbase + qrow) * DMODEL + colbase + n * 16 + cl;
        Oh[idx] = f2bf(ov);
      }
}

extern "C" void kernel_launch(void* const* d_in, const int* in_sizes, int n_in,
                              void* d_out, int out_size, void* d_ws, size_t ws_size,
                              hipStream_t stream) {
  const float* x  = (const float*)d_in[0];
  const float* Wq = (const float*)d_in[1];
  const float* Wk = (const float*)d_in[2];
  const float* Wv = (const float*)d_in[3];
  const float* Wo = (const float*)d_in[4];
  float* out = (float*)d_out;

  const int M = NB * SEQ;      // 4096
  const int D = DMODEL;        // 1024
  char* ws = (char*)d_ws;
  const size_t MB = 1u << 20;
  u16* xh16 = (u16*)(ws + 0 * MB);    // 8 MB fp16
  u16* qh16 = (u16*)(ws + 8 * MB);    // 8 MB fp16 (unrotated; attn rotates Q)
  u16* kh16 = (u16*)(ws + 16 * MB);   // 8 MB fp16 (rotated in place)
  u16* vt   = (u16*)(ws + 24 * MB);   // 8 MB bf16, transposed [1024][4096]
  u16* oh   = (u16*)(ws + 40 * MB);   // 8 MB bf16
  u16* wq16 = (u16*)(ws + 48 * MB);   // 2 MB each
  u16* wk16 = (u16*)(ws + 50 * MB);
  u16* wv16 = (u16*)(ws + 52 * MB);
  u16* wob  = (u16*)(ws + 54 * MB);

  // one fused cast launch: x,Wq,Wk,Wv -> fp16 ; Wo -> bf16
  {
    int total = M * D / 8 + 4 * (D * D / 8);
    cast_all_kernel<<<(total + 255) / 256, 256, 0, stream>>>(
        x, Wq, Wk, Wv, Wo, xh16, wq16, wk16, wv16, wob);
  }

  // QKV: z=0 fused Q+K shared-A pair blocks; z=1 V (Vt out). 512 blocks.
  qkv_kernel<<<dim3(D / 128, M / 128, 2), 256, 0, stream>>>(
      xh16, wq16, wk16, wv16, qh16, kh16, vt, M, D, D);

  // RoPE on K only (Q rotated in attn): one thread per (row, freq), 16 pairs each
  rope_k_kernel<<<(M * 32) / 256, 256, 0, stream>>>(kh16);

  // causal flash attention: 512 blocks of 4 waves, pair-balanced heavy-first
  attn_kernel<<<dim3(NH * NB, 8), 256, 0, stream>>>(qh16, kh16, vt, oh);

  // output projection: bf16, 128x64 tile, counted-vmcnt dbuf, direct f32 out
  gemm_wo_kernel<<<dim3(D / 64, M / 128, 1), 256, 0, stream>>>(
      oh, wob, out, M, D, D);
}